// Round 6
// baseline (88.810 us; speedup 1.0000x reference)
//
#include <hip/hip_runtime.h>

// GAT block, algebraically collapsed:
//   d[b,f,n]     = softmax_n( x[b,:,f,n] . (W @ a2) )[n] * mask[n,n]
//   out[b,h,f,n] = d[b,f,n] * (sum_c x[b,c,f,n]*W[c,h] + bW[h])
// (s1, ab, bW.a2 cancel inside the row-softmax — constant over the softmax axis.)
//
// R6: uniform tiling. 64-frame chunks (1600 floats = 400 float4, frame-aligned,
// no halo), 1024 blocks = exactly 4 blocks/CU resident. NT stores (R5 A/B showed
// +5us win), packed W float4 broadcast, x/d in registers for the write loop.

typedef float vfloat4 __attribute__((ext_vector_type(4)));

namespace {
constexpr int B_ = 32, C_ = 3, F_ = 2048, N_ = 25, H_ = 64;
constexpr int FN   = F_ * N_;       // 51200 floats per (b,c)/(b,h) plane
constexpr int FN4  = FN / 4;        // 12800 float4 slots per plane
constexpr int TF   = 64;            // frames per chunk
constexpr int TPOS = TF * N_;       // 1600 floats per chunk
constexpr int TVEC = TPOS / 4;      // 400 float4 slots per chunk
constexpr int THREADS = 256;
}

__global__ __launch_bounds__(THREADS) void gat_fused3(
    const float* __restrict__ x, const float* __restrict__ mask,
    const float* __restrict__ W, const float* __restrict__ bW,
    const float* __restrict__ a2, float* __restrict__ out)
{
  __shared__ vfloat4 x4[3][TVEC];   // x chunk, per channel
  __shared__ vfloat4 d4[TVEC];      // diag-scale per position
  __shared__ vfloat4 Wp[H_];        // {W0[h], W1[h], W2[h], bW[h]}
  __shared__ float   mdl[N_];
  __shared__ float   wal[C_];

  const int tid = threadIdx.x;
  const int blk = blockIdx.x;       // 0..1023
  const int b   = blk >> 5;
  const int ft  = blk & 31;
  const size_t fbase4 = (size_t)ft * TVEC;   // float4 offset inside plane

  // ---- stage: x chunk -> LDS; pack W; wa = W@a2; mask diag ----
  const vfloat4* xg = (const vfloat4*)x;
  {
    vfloat4* dst = &x4[0][0];
    for (int i = tid; i < 3 * TVEC; i += THREADS) {
      const int c = i / TVEC;
      const int j = i - c * TVEC;
      dst[i] = xg[(size_t)(b * 3 + c) * FN4 + fbase4 + j];
    }
  }
  if (tid < H_) {
    vfloat4 w = {W[tid], W[H_ + tid], W[2 * H_ + tid], bW[tid]};
    Wp[tid] = w;
  } else if (tid < H_ + C_) {
    const int c = tid - H_;
    float s = 0.f;
    for (int h = 0; h < H_; ++h) s += W[c * H_ + h] * a2[h];
    wal[c] = s;
  }
  if (tid >= 128 && tid < 128 + N_) mdl[tid - 128] = mask[(tid - 128) * (N_ + 1)];
  __syncthreads();

  // ---- per-frame 25-way softmax -> d4 (one wave covers 64 frames) ----
  if (tid < TF) {
    const float* xl0 = (const float*)&x4[0][0];
    const float* xl1 = (const float*)&x4[1][0];
    const float* xl2 = (const float*)&x4[2][0];
    const float wa0 = wal[0], wa1 = wal[1], wa2 = wal[2];
    const int base = tid * N_;
    float s[N_];
    float m = -3.0e38f;
#pragma unroll
    for (int n = 0; n < N_; ++n) {
      float v = fmaf(xl2[base + n], wa2,
                fmaf(xl1[base + n], wa1, xl0[base + n] * wa0));
      s[n] = v;
      m = fmaxf(m, v);
    }
    float z = 0.f;
#pragma unroll
    for (int n = 0; n < N_; ++n) { s[n] = __expf(s[n] - m); z += s[n]; }
    const float inv = 1.f / z;
    float* dl = (float*)d4;
#pragma unroll
    for (int n = 0; n < N_; ++n) dl[base + n] = s[n] * inv * mdl[n];
  }
  __syncthreads();

  // ---- write phase: x/d in registers, NT float4 stores ----
  // thread owns slots {tid, tid+256}; second exists only for tid<144.
  const bool has2 = tid < (TVEC - THREADS);
  const vfloat4 xa0 = x4[0][tid];
  const vfloat4 xa1 = x4[1][tid];
  const vfloat4 xa2 = x4[2][tid];
  const vfloat4 da  = d4[tid];
  vfloat4 xb0 = {}, xb1 = {}, xb2 = {}, db = {};
  if (has2) {
    xb0 = x4[0][tid + THREADS];
    xb1 = x4[1][tid + THREADS];
    xb2 = x4[2][tid + THREADS];
    db  = d4[tid + THREADS];
  }

  vfloat4* og = (vfloat4*)out;
  const size_t ob = (size_t)b * H_ * FN4 + fbase4 + tid;
#pragma unroll 4
  for (int h = 0; h < H_; ++h) {
    const vfloat4 wv = Wp[h];            // one broadcast ds_read_b128
    vfloat4 o;
    o.x = da.x * fmaf(xa2.x, wv.z, fmaf(xa1.x, wv.y, fmaf(xa0.x, wv.x, wv.w)));
    o.y = da.y * fmaf(xa2.y, wv.z, fmaf(xa1.y, wv.y, fmaf(xa0.y, wv.x, wv.w)));
    o.z = da.z * fmaf(xa2.z, wv.z, fmaf(xa1.z, wv.y, fmaf(xa0.z, wv.x, wv.w)));
    o.w = da.w * fmaf(xa2.w, wv.z, fmaf(xa1.w, wv.y, fmaf(xa0.w, wv.x, wv.w)));
    __builtin_nontemporal_store(o, &og[ob + (size_t)h * FN4]);
    if (has2) {
      vfloat4 o2;
      o2.x = db.x * fmaf(xb2.x, wv.z, fmaf(xb1.x, wv.y, fmaf(xb0.x, wv.x, wv.w)));
      o2.y = db.y * fmaf(xb2.y, wv.z, fmaf(xb1.y, wv.y, fmaf(xb0.y, wv.x, wv.w)));
      o2.z = db.z * fmaf(xb2.z, wv.z, fmaf(xb1.z, wv.y, fmaf(xb0.z, wv.x, wv.w)));
      o2.w = db.w * fmaf(xb2.w, wv.z, fmaf(xb1.w, wv.y, fmaf(xb0.w, wv.x, wv.w)));
      __builtin_nontemporal_store(o2, &og[ob + (size_t)h * FN4 + THREADS]);
    }
  }
}

extern "C" void kernel_launch(void* const* d_in, const int* in_sizes, int n_in,
                              void* d_out, int out_size, void* d_ws, size_t ws_size,
                              hipStream_t stream) {
  const float* x    = (const float*)d_in[0];  // [B,C,F,N]
  const float* mask = (const float*)d_in[1];  // [N,N]
  const float* W    = (const float*)d_in[2];  // [C,H]
  const float* bW   = (const float*)d_in[3];  // [H]
  // d_in[4] = a1 (cancels), d_in[6] = ab (cancels)
  const float* a2   = (const float*)d_in[5];  // [H]
  float* out = (float*)d_out;                 // [B,H,F,N]

  hipLaunchKernelGGL(gat_fused3, dim3(B_ * (F_ / TF)), dim3(THREADS), 0, stream,
                     x, mask, W, bW, a2, out);
}

// Round 7
// 82.455 us; speedup vs baseline: 1.0771x; 1.0771x over previous
//
#include <hip/hip_runtime.h>

// GAT block, algebraically collapsed:
//   d[b,f,n]     = softmax_n( x[b,:,f,n] . (W @ a2) )[n] * mask[n,n]
//   out[b,h,f,n] = d[b,f,n] * (sum_c x[b,c,f,n]*W[c,h] + bW[h])
// (s1, ab, bW.a2 cancel inside the row-softmax — constant over the softmax axis.)
//
// R7 = R4 (best: 81.4us; 1-slot/thread, NT stores, unroll 4) + ONE change:
// LDS padding forces occupancy 8 -> 2 blocks/CU (8 waves/CU) to test whether
// 800+ concurrent NT store streams were thrashing the memory system
// (fill kernel hits 7 TB/s at ~3.4 waves/CU).

typedef float vfloat4 __attribute__((ext_vector_type(4)));

namespace {
constexpr int B_ = 32, C_ = 3, F_ = 2048, N_ = 25, H_ = 64;
constexpr int FN   = F_ * N_;      // 51200 floats per (b,c)/(b,h) plane
constexpr int FN4  = FN / 4;       // 12800 float4 slots per plane
constexpr int THREADS = 256;
constexpr int JB   = FN4 / THREADS; // 50 blocks per plane
constexpr int MAXW = 264;          // max float4 window per channel (<=1056 floats)
constexpr int PAD4 = 2688;         // 43 KB LDS pad -> ~61 KB total -> 2 blocks/CU
}

__global__ __launch_bounds__(THREADS) void gat_fused2(
    const float* __restrict__ x, const float* __restrict__ mask,
    const float* __restrict__ W, const float* __restrict__ bW,
    const float* __restrict__ a2, float* __restrict__ out)
{
  __shared__ float   xl[3][4 * MAXW];   // x window, per channel
  __shared__ float   dl[4 * MAXW];      // diag-scale per position in window
  __shared__ vfloat4 Wp[H_];            // {W0[h], W1[h], W2[h], bW[h]}
  __shared__ float   mdl[N_];
  __shared__ float   wal[C_];
  __shared__ vfloat4 padlds[PAD4];      // occupancy limiter (kept alive below)

  const int tid = threadIdx.x;
  const int blk = blockIdx.x;
  const int b   = blk / JB;
  const int jb  = blk - b * JB;
  const int S   = jb * THREADS;         // float4 slot base within plane
  const int p0  = S * 4;                // first float position of this block
  const int f0  = p0 / N_;
  const int f1  = (p0 + 4 * THREADS - 1) / N_;
  const int nf  = f1 - f0 + 1;          // <= 42 frames
  const int A0  = (f0 * N_) & ~3;       // aligned window start (floats)
  int A1 = (f1 * N_ + N_ + 3) & ~3;     // aligned window end
  if (A1 > FN) A1 = FN;
  const int cnt4 = (A1 - A0) >> 2;      // <= MAXW

  // ---- stage: x window -> LDS; pack W; wa = W@a2; mask diag ----
  const vfloat4* xg = (const vfloat4*)x;
#pragma unroll
  for (int c = 0; c < 3; ++c) {
    const vfloat4* src = xg + (size_t)(b * 3 + c) * FN4 + (A0 >> 2);
    vfloat4* dst = (vfloat4*)xl[c];
    for (int i = tid; i < cnt4; i += THREADS) dst[i] = src[i];
  }
  if (tid < H_) {
    vfloat4 w = {W[tid], W[H_ + tid], W[2 * H_ + tid], bW[tid]};
    Wp[tid] = w;
  } else if (tid < H_ + C_) {
    const int c = tid - H_;
    float s = 0.f;
    for (int h = 0; h < H_; ++h) s += W[c * H_ + h] * a2[h];
    wal[c] = s;
  }
  if (tid >= 128 && tid < 128 + N_) mdl[tid - 128] = mask[(tid - 128) * (N_ + 1)];
  __syncthreads();

  // ---- per-frame 25-way softmax -> dl (one wave covers all <=42 frames) ----
  if (tid < nf) {
    const float wa0 = wal[0], wa1 = wal[1], wa2 = wal[2];
    const int base = (f0 + tid) * N_ - A0;
    float s[N_];
    float m = -3.0e38f;
#pragma unroll
    for (int n = 0; n < N_; ++n) {
      float v = fmaf(xl[2][base + n], wa2,
                fmaf(xl[1][base + n], wa1, xl[0][base + n] * wa0));
      s[n] = v;
      m = fmaxf(m, v);
    }
    float z = 0.f;
#pragma unroll
    for (int n = 0; n < N_; ++n) { s[n] = __expf(s[n] - m); z += s[n]; }
    const float inv = 1.f / z;
#pragma unroll
    for (int n = 0; n < N_; ++n) dl[base + n] = s[n] * inv * mdl[n];
  }
  __syncthreads();

  // ---- write phase: x/d in registers, 64 NT float4 stores ----
  const int li = tid + S - (A0 >> 2);   // this thread's float4 index in window
  const vfloat4 x0 = ((const vfloat4*)xl[0])[li];
  const vfloat4 x1 = ((const vfloat4*)xl[1])[li];
  const vfloat4 x2 = ((const vfloat4*)xl[2])[li];
  const vfloat4 dd = ((const vfloat4*)dl)[li];

  // keep the LDS pad alive: data-dependent, never-true store
  if (dl[0] == 1.0e30f) padlds[tid] = dd;

  vfloat4* og = (vfloat4*)out;
  const size_t ob = (size_t)b * H_ * FN4 + S + tid;
#pragma unroll 4
  for (int h = 0; h < H_; ++h) {
    const vfloat4 wv = Wp[h];            // one broadcast ds_read_b128
    vfloat4 o;
    o.x = dd.x * fmaf(x2.x, wv.z, fmaf(x1.x, wv.y, fmaf(x0.x, wv.x, wv.w)));
    o.y = dd.y * fmaf(x2.y, wv.z, fmaf(x1.y, wv.y, fmaf(x0.y, wv.x, wv.w)));
    o.z = dd.z * fmaf(x2.z, wv.z, fmaf(x1.z, wv.y, fmaf(x0.z, wv.x, wv.w)));
    o.w = dd.w * fmaf(x2.w, wv.z, fmaf(x1.w, wv.y, fmaf(x0.w, wv.x, wv.w)));
    __builtin_nontemporal_store(o, &og[ob + (size_t)h * FN4]);
  }
}

extern "C" void kernel_launch(void* const* d_in, const int* in_sizes, int n_in,
                              void* d_out, int out_size, void* d_ws, size_t ws_size,
                              hipStream_t stream) {
  const float* x    = (const float*)d_in[0];  // [B,C,F,N]
  const float* mask = (const float*)d_in[1];  // [N,N]
  const float* W    = (const float*)d_in[2];  // [C,H]
  const float* bW   = (const float*)d_in[3];  // [H]
  // d_in[4] = a1 (cancels), d_in[6] = ab (cancels)
  const float* a2   = (const float*)d_in[5];  // [H]
  float* out = (float*)d_out;                 // [B,H,F,N]

  hipLaunchKernelGGL(gat_fused2, dim3(B_ * JB), dim3(THREADS), 0, stream,
                     x, mask, W, bW, a2, out);
}